// Round 7
// baseline (184.024 us; speedup 1.0000x reference)
//
#include <hip/hip_runtime.h>

#define B_ROWS 8192
#define FEAT   256
#define NCCH   16          // j-tile residue classes -> grid = 16 x 32 = 512 blocks
#define NJTILE 128         // total 64-col j-tiles

typedef float f32x4 __attribute__((ext_vector_type(4)));
typedef _Float16 f16x8 __attribute__((ext_vector_type(8)));

typedef const __attribute__((address_space(1))) unsigned int* gas_ptr;
typedef __attribute__((address_space(3))) unsigned int* las_ptr;

__device__ __forceinline__ void gload_lds16(const void* g, void* l) {
  // HW semantics: LDS dest = wave-uniform base + lane*16
  __builtin_amdgcn_global_load_lds((gas_ptr)g, (las_ptr)l, 16, 0, 0);
}

// ---- kernel 1: fp16 convert, row ssq, per-block f32 partials (R10, proven)
// zeroes all four atomic accumulator arrays (row_*/col_*)
__global__ __launch_bounds__(256) void prep_kernel(
    const float* __restrict__ x, unsigned short* __restrict__ xh,
    float* __restrict__ sq, float* __restrict__ part_s,
    float* __restrict__ part_q, float* __restrict__ col_den,
    float* __restrict__ col_num, float* __restrict__ row_den,
    float* __restrict__ row_num)
{
  int tid = threadIdx.x;
  int l = tid & 63, wid = tid >> 6;
  int row = blockIdx.x * 4 + wid;
  const float4* xv = (const float4*)(x + (size_t)row * FEAT);
  float4 v = xv[l];
  ushort4 u;
  u.x = __builtin_bit_cast(unsigned short, (_Float16)v.x);
  u.y = __builtin_bit_cast(unsigned short, (_Float16)v.y);
  u.z = __builtin_bit_cast(unsigned short, (_Float16)v.z);
  u.w = __builtin_bit_cast(unsigned short, (_Float16)v.w);
  ((ushort4*)(xh + (size_t)row * FEAT))[l] = u;
  if (tid < 4) {
    int r4 = blockIdx.x * 4 + tid;
    col_den[r4] = 0.f; col_num[r4] = 0.f;
    row_den[r4] = 0.f; row_num[r4] = 0.f;
  }
  float ssq  = v.x*v.x + v.y*v.y + v.z*v.z + v.w*v.w;
  float ssum = v.x + v.y + v.z + v.w;
  #pragma unroll
  for (int m = 32; m; m >>= 1) {
    ssq  += __shfl_xor(ssq, m);
    ssum += __shfl_xor(ssum, m);
  }
  if (l == 0) sq[row] = ssq;
  __shared__ float red[8];
  if (l == 0) { red[wid*2] = ssum; red[wid*2+1] = ssq; }
  __syncthreads();
  if (tid == 0) {
    part_s[blockIdx.x] = red[0]+red[2]+red[4]+red[6];
    part_q[blockIdx.x] = red[1]+red[3]+red[5]+red[7];
  }
}

// ---- epilogue: wave tile 32(i) x 64(j). Fully self-contained (R6b register
// trim): loads row stats from memory (quad-uniform broadcast, L1-hot) and
// pushes row sums via quad shuffle-reduce + atomicAdd per tile -- the exact
// mirror of the proven col-atomic path. No persistent per-row state.
// DIAG: band tile (mask i==j), row-sums only.
// COL : far tile -- also col-sums (symmetric credit to rows j).
template<bool DIAG, bool COL>
__device__ __forceinline__ void epilogue(
    const f32x4 (&acc)[2][4], const float* __restrict__ sq,
    const int* __restrict__ y, int j0, int l15, int l,
    int rbase, float nscale2,
    float* __restrict__ row_den, float* __restrict__ row_num,
    float* __restrict__ col_den, float* __restrict__ col_num)
{
  int jb = j0 + l15;
  float sqj[4]; int yj[4];
  #pragma unroll
  for (int cb = 0; cb < 4; ++cb) {
    int j = jb + cb*16;
    sqj[cb] = sq[j];
    yj[cb]  = y[j];
  }
  float cd[4], cn[4];
  if (COL) {
    #pragma unroll
    for (int cb = 0; cb < 4; ++cb) { cd[cb] = 0.f; cn[cb] = 0.f; }
  }
  #pragma unroll
  for (int rb = 0; rb < 2; ++rb) {
    #pragma unroll
    for (int r = 0; r < 4; ++r) {
      int   ig = rbase + rb*16 + r;     // same for all 16 lanes of the quad
      float si = sq[ig];
      int   yi = y[ig];
      float dacc = 0.f, nacc = 0.f;
      #pragma unroll
      for (int cb = 0; cb < 4; ++cb) {
        float S  = acc[rb][cb][r];
        float d2 = fmaf(S, -2.0f, si + sqj[cb]);
        d2 = fmaxf(d2, 0.0f);
        float e  = __builtin_amdgcn_exp2f(__builtin_amdgcn_sqrtf(d2) * nscale2);
        bool same = (yi == yj[cb]);
        bool offd = !DIAG || (ig != jb + cb*16);
        dacc += offd ? e : 0.0f;
        nacc += (same && offd) ? e : 0.0f;
        if (COL) {
          cd[cb] += e;
          cn[cb] += same ? e : 0.0f;
        }
      }
      // row-sum: reduce across the 16 lanes of the quad, then one atomic
      #pragma unroll
      for (int m = 1; m <= 8; m <<= 1) {
        dacc += __shfl_xor(dacc, m);
        nacc += __shfl_xor(nacc, m);
      }
      if (l15 == 0) {
        atomicAdd(&row_den[ig], dacc);
        atomicAdd(&row_num[ig], nacc);
      }
    }
  }
  if (COL) {
    #pragma unroll
    for (int cb = 0; cb < 4; ++cb) {
      cd[cb] += __shfl_xor(cd[cb], 16);
      cd[cb] += __shfl_xor(cd[cb], 32);
      cn[cb] += __shfl_xor(cn[cb], 16);
      cn[cb] += __shfl_xor(cn[cb], 32);
    }
    if (l < 16) {
      #pragma unroll
      for (int cb = 0; cb < 4; ++cb) {
        atomicAdd(&col_den[j0 + cb*16 + l], cd[cb]);
        atomicAdd(&col_num[j0 + cb*16 + l], cn[cb]);
      }
    }
  }
}

// ---- kernel 2 (R16 structure, resubmitted after infra failure with R6b
// register trim): grid 16 x 32 = 512 blocks. Block (c, p) owns row-blocks
// p and q=63-p. q's j-tile set {jt ≡ c mod 16, jt >= 126-2p} is a SUBSET of
// p's {jt >= 2p}, so ONE loop over p's tiles stages each B tile ONCE and
// feeds BOTH rows' MFMAs from the same bv fragments (acc_q active when
// jt >= 126-2p). Per compute-tile this halves staging, barriers, ds_reads
// and bank conflicts vs R15 (R15 lesson: per-staged-tile overhead dominated;
// pipes 29%/12% busy, rest idle).
// Register budget (R6b): aregp/aregq 128 + accp/accq 64 + temps ~40 = ~230
// VGPR < 256 cap -> no spill (R16's persistent stats arrays pushed demand
// to ~290; trimmed via self-contained epilogue).
__global__ __launch_bounds__(256, 2) void snn_main(
    const unsigned short* __restrict__ xh, const float* __restrict__ sq,
    const int* __restrict__ y, const float* __restrict__ T,
    const float* __restrict__ part_s, const float* __restrict__ part_q,
    float* __restrict__ row_den, float* __restrict__ row_num,
    float* __restrict__ col_den, float* __restrict__ col_num)
{
  __shared__ __align__(16) char lB[32768];
  int tid = threadIdx.x;
  int l = tid & 63, wid = tid >> 6;     // wid = wave row strip (0..3)
  int quad = l >> 4, l15 = l & 15;
  int l5 = l >> 5, s31 = l & 31;
  int c = blockIdx.x, p = blockIdx.y;   // p in [0,32)
  int q = 63 - p;
  int i0p = p * 128, i0q = q * 128;
  int jq0 = 2 * q;                      // q active for jt >= jq0 (=126-2p)
  const char* xbc = (const char*)xh;

  // A fragments for both rows: lane holds A[m = i0+wid*32+rb*16+l15]
  // [k = kk*32 + quad*8 .. +8] = 16 B at row*512 + kk*64 + quad*16
  f16x8 aregp[2][8], aregq[2][8];
  #pragma unroll
  for (int rb = 0; rb < 2; ++rb)
    #pragma unroll
    for (int kk = 0; kk < 8; ++kk) {
      size_t off = (size_t)(wid*32 + rb*16 + l15)*512 + kk*64 + quad*16;
      aregp[rb][kk] = *(const f16x8*)(xbc + (size_t)i0p*512 + off);
      aregq[rb][kk] = *(const f16x8*)(xbc + (size_t)i0q*512 + off);
    }

  // scale from prep's 2048 partials (per-wave redundant; no barrier)
  float s_acc = 0.f, q_acc = 0.f;
  #pragma unroll
  for (int t = 0; t < 32; ++t) {
    s_acc += part_s[l + 64*t];
    q_acc += part_q[l + 64*t];
  }
  #pragma unroll
  for (int m = 1; m <= 32; m <<= 1) {
    s_acc += __shfl_xor(s_acc, m);
    q_acc += __shfl_xor(q_acc, m);
  }
  const double n = (double)B_ROWS * FEAT;
  double var = ((double)q_acc - (double)s_acc*(double)s_acc/n) / (n - 1.0);
  float stdv = (float)sqrt(var);
  float p10  = __builtin_amdgcn_exp2f(T[0] * 3.3219280948873623f);
  float nscale2 = -(p10 * 1.4426950408889634f / stdv);

  int rbasep = i0p + wid*32 + quad*4;
  int rbaseq = i0q + wid*32 + quad*4;

  f32x4 accp[2][4], accq[2][4];
  const f32x4 zero4 = {0.f, 0.f, 0.f, 0.f};

  // first j-tile: smallest jt >= 2p with jt ≡ c (mod 16)
  int f = 2*p + ((c - 2*p) & (NCCH-1));
  int pjt = -1; bool ppq = false;

  for (int jt = f; jt < NJTILE; jt += NCCH) {
    int j0 = jt * 64;

    __syncthreads();   // all waves done reading lB of previous tile
    // stage B tile jt (64 cols x 512 B = 32 chunks of 1024 B) to LDS
    {
      const char* gB = xbc + (size_t)j0 * 512;
      #pragma unroll
      for (int s = 0; s < 8; ++s) {
        int cc = wid*8 + s;
        int rw = 2*cc + l5;
        int gg = s31 ^ (rw & 7);
        gload_lds16(gB + rw*512 + gg*16, lB + cc*1024);
      }
    }

    if (pjt >= 0) {
      int pj0 = pjt * 64;
      if ((pjt >> 1) == p)
        epilogue<true , false>(accp, sq, y, pj0, l15, l, rbasep, nscale2,
                               row_den, row_num, col_den, col_num);
      else
        epilogue<false, true >(accp, sq, y, pj0, l15, l, rbasep, nscale2,
                               row_den, row_num, col_den, col_num);
      if (ppq) {
        if ((pjt >> 1) == q)
          epilogue<true , false>(accq, sq, y, pj0, l15, l, rbaseq, nscale2,
                                 row_den, row_num, col_den, col_num);
        else
          epilogue<false, true >(accq, sq, y, pj0, l15, l, rbaseq, nscale2,
                                 row_den, row_num, col_den, col_num);
      }
    }
    #pragma unroll
    for (int rb = 0; rb < 2; ++rb)
      #pragma unroll
      for (int cb = 0; cb < 4; ++cb) {
        accp[rb][cb] = zero4;
        accq[rb][cb] = zero4;
      }

    __syncthreads();   // drains vmcnt: B tile visible

    bool qact = (jt >= jq0);
    #pragma unroll
    for (int kk = 0; kk < 8; ++kk) {
      f16x8 bv[4];
      #pragma unroll
      for (int cb = 0; cb < 4; ++cb) {
        int nr = cb*16 + l15;
        bv[cb] = *(const f16x8*)(lB + nr*512 + ((((kk<<2)|quad) ^ (l15 & 7)) << 4));
      }
      #pragma unroll
      for (int rb = 0; rb < 2; ++rb)
        #pragma unroll
        for (int cb = 0; cb < 4; ++cb)
          accp[rb][cb] = __builtin_amdgcn_mfma_f32_16x16x32_f16(aregp[rb][kk], bv[cb], accp[rb][cb], 0, 0, 0);
      if (qact) {
        #pragma unroll
        for (int rb = 0; rb < 2; ++rb)
          #pragma unroll
          for (int cb = 0; cb < 4; ++cb)
            accq[rb][cb] = __builtin_amdgcn_mfma_f32_16x16x32_f16(aregq[rb][kk], bv[cb], accq[rb][cb], 0, 0, 0);
      }
    }
    pjt = jt; ppq = qact;
  }
  {
    int pj0 = pjt * 64;
    if ((pjt >> 1) == p)
      epilogue<true , false>(accp, sq, y, pj0, l15, l, rbasep, nscale2,
                             row_den, row_num, col_den, col_num);
    else
      epilogue<false, true >(accp, sq, y, pj0, l15, l, rbasep, nscale2,
                             row_den, row_num, col_den, col_num);
    if (ppq) {
      if ((pjt >> 1) == q)
        epilogue<true , false>(accq, sq, y, pj0, l15, l, rbaseq, nscale2,
                               row_den, row_num, col_den, col_num);
      else
        epilogue<false, true >(accq, sq, y, pj0, l15, l, rbaseq, nscale2,
                               row_den, row_num, col_den, col_num);
    }
  }
}

// ---- kernel 3: single 1024-thread block; reads only 4 x 32 KB.
// __builtin_amdgcn_logf is LOG2 -> scale by ln(2)  (R4/5/7/9 bug).
__global__ __launch_bounds__(1024) void final_kernel(
    const float* __restrict__ row_den, const float* __restrict__ row_num,
    const float* __restrict__ col_den, const float* __restrict__ col_num,
    float* __restrict__ out)
{
  int tid = threadIdx.x;
  float tot = 0.f;
  #pragma unroll
  for (int rr = 0; rr < 8; ++rr) {
    int row = tid + 1024*rr;
    float den = row_den[row] + col_den[row];
    float num = row_num[row] + col_num[row];
    if (num > 0.f)
      tot += 0.6931471805599453f *
             (__builtin_amdgcn_logf(num) - __builtin_amdgcn_logf(den));
  }
  #pragma unroll
  for (int m = 32; m; m >>= 1) tot += __shfl_xor(tot, m);
  __shared__ float red[16];
  if ((tid & 63) == 0) red[tid >> 6] = tot;
  __syncthreads();
  if (tid == 0) {
    float s = 0.f;
    #pragma unroll
    for (int w = 0; w < 16; ++w) s += red[w];
    out[0] = -s / 8192.0f;
  }
}

extern "C" void kernel_launch(void* const* d_in, const int* in_sizes, int n_in,
                              void* d_out, int out_size, void* d_ws, size_t ws_size,
                              hipStream_t stream)
{
  (void)in_sizes; (void)n_in; (void)out_size; (void)ws_size;
  const float* x  = (const float*)d_in[0];
  const int* y    = (const int*)d_in[1];   // int64 in reference -> int32 here (jax x64 off)
  const float* T  = (const float*)d_in[2];
  char* ws = (char*)d_ws;
  float* part_s = (float*)(ws + 1024);                   // 8 KB
  float* part_q = (float*)(ws + 1024 + 8192);            // 8 KB
  float* sq     = (float*)(ws + 32768);                  // 32 KB
  unsigned short* xh = (unsigned short*)(ws + 65536);    // 4 MB fp16
  float* col_den = (float*)(ws + 65536 + 4194304);       // 32 KB
  float* col_num = col_den + B_ROWS;                     // 32 KB
  float* row_den = col_num + B_ROWS;                     // 32 KB
  float* row_num = row_den + B_ROWS;                     // 32 KB

  hipLaunchKernelGGL(prep_kernel, dim3(B_ROWS/4), dim3(256), 0, stream,
                     x, xh, sq, part_s, part_q, col_den, col_num,
                     row_den, row_num);
  hipLaunchKernelGGL(snn_main, dim3(NCCH, 32), dim3(256), 0, stream,
                     xh, sq, y, T, part_s, part_q, row_den, row_num,
                     col_den, col_num);
  hipLaunchKernelGGL(final_kernel, dim3(1), dim3(1024), 0, stream,
                     row_den, row_num, col_den, col_num, (float*)d_out);
}

// Round 8
// 145.162 us; speedup vs baseline: 1.2677x; 1.2677x over previous
//
#include <hip/hip_runtime.h>

#define B_ROWS 8192
#define FEAT   256
#define NCCH   16          // j-tile residue classes -> grid = 16 x 32 = 512 blocks
#define NJTILE 128         // total 64-col j-tiles

typedef float f32x4 __attribute__((ext_vector_type(4)));
typedef _Float16 f16x8 __attribute__((ext_vector_type(8)));

// ---- kernel 1: fp16 convert -> FRAGMENT-NATIVE layout, row ssq, partials.
// R17 layout: xh is stored as 1024-B chunks, one per (16-row group C, kk):
//   chunk(C,kk) byte (quad*256 + r15*16 + h*8) = x[C*16+r15][kk*32+quad*8+h*4 ..+4]
// i.e. byte l*16 of chunk(C,kk) is exactly lane l's 16-B MFMA fragment for
// rows C*16..C*16+15, k-slice kk. Both A and B fragment loads in snn_main
// become single coalesced global_load_dwordx4 (base + l*16) -> no LDS at all.
// Also zeroes all four atomic accumulator arrays.
__global__ __launch_bounds__(256) void prep_kernel(
    const float* __restrict__ x, unsigned short* __restrict__ xh,
    float* __restrict__ sq, float* __restrict__ part_s,
    float* __restrict__ part_q, float* __restrict__ col_den,
    float* __restrict__ col_num, float* __restrict__ row_den,
    float* __restrict__ row_num)
{
  int tid = threadIdx.x;
  int l = tid & 63, wid = tid >> 6;
  int row = blockIdx.x * 4 + wid;
  const float4* xv = (const float4*)(x + (size_t)row * FEAT);
  float4 v = xv[l];            // cols 4l .. 4l+3
  ushort4 u;
  u.x = __builtin_bit_cast(unsigned short, (_Float16)v.x);
  u.y = __builtin_bit_cast(unsigned short, (_Float16)v.y);
  u.z = __builtin_bit_cast(unsigned short, (_Float16)v.z);
  u.w = __builtin_bit_cast(unsigned short, (_Float16)v.w);
  // k0 = 4l: kk = l>>3, quad = (l>>1)&3, half-of-16B = l&1
  size_t off = ((size_t)(row >> 4) * 8 + (l >> 3)) * 1024
             + ((l >> 1) & 3) * 256 + (row & 15) * 16 + (l & 1) * 8;
  *(ushort4*)((char*)xh + off) = u;
  if (tid < 4) {
    int r4 = blockIdx.x * 4 + tid;
    col_den[r4] = 0.f; col_num[r4] = 0.f;
    row_den[r4] = 0.f; row_num[r4] = 0.f;
  }
  float ssq  = v.x*v.x + v.y*v.y + v.z*v.z + v.w*v.w;
  float ssum = v.x + v.y + v.z + v.w;
  #pragma unroll
  for (int m = 32; m; m >>= 1) {
    ssq  += __shfl_xor(ssq, m);
    ssum += __shfl_xor(ssum, m);
  }
  if (l == 0) sq[row] = ssq;
  __shared__ float red[8];
  if (l == 0) { red[wid*2] = ssum; red[wid*2+1] = ssq; }
  __syncthreads();
  if (tid == 0) {
    part_s[blockIdx.x] = red[0]+red[2]+red[4]+red[6];
    part_q[blockIdx.x] = red[1]+red[3]+red[5]+red[7];
  }
}

// ---- epilogue: wave tile 32(i) x 64(j). Self-contained (R6b): loads row
// stats from memory (quad-uniform broadcast, L1-hot) and pushes row sums via
// quad shuffle-reduce + atomicAdd per tile; col sums likewise for far tiles.
// DIAG: band tile (mask i==j), row-sums only.
// COL : far tile -- also col-sums (symmetric credit e(i,j)=e(j,i)).
template<bool DIAG, bool COL>
__device__ __forceinline__ void epilogue(
    const f32x4 (&acc)[2][4], const float* __restrict__ sq,
    const int* __restrict__ y, int j0, int l15, int l,
    int rbase, float nscale2,
    float* __restrict__ row_den, float* __restrict__ row_num,
    float* __restrict__ col_den, float* __restrict__ col_num)
{
  int jb = j0 + l15;
  float sqj[4]; int yj[4];
  #pragma unroll
  for (int cb = 0; cb < 4; ++cb) {
    int j = jb + cb*16;
    sqj[cb] = sq[j];
    yj[cb]  = y[j];
  }
  float cd[4], cn[4];
  if (COL) {
    #pragma unroll
    for (int cb = 0; cb < 4; ++cb) { cd[cb] = 0.f; cn[cb] = 0.f; }
  }
  #pragma unroll
  for (int rb = 0; rb < 2; ++rb) {
    #pragma unroll
    for (int r = 0; r < 4; ++r) {
      int   ig = rbase + rb*16 + r;     // same for all 16 lanes of the quad
      float si = sq[ig];
      int   yi = y[ig];
      float dacc = 0.f, nacc = 0.f;
      #pragma unroll
      for (int cb = 0; cb < 4; ++cb) {
        float S  = acc[rb][cb][r];
        float d2 = fmaf(S, -2.0f, si + sqj[cb]);
        d2 = fmaxf(d2, 0.0f);
        float e  = __builtin_amdgcn_exp2f(__builtin_amdgcn_sqrtf(d2) * nscale2);
        bool same = (yi == yj[cb]);
        bool offd = !DIAG || (ig != jb + cb*16);
        dacc += offd ? e : 0.0f;
        nacc += (same && offd) ? e : 0.0f;
        if (COL) {
          cd[cb] += e;
          cn[cb] += same ? e : 0.0f;
        }
      }
      #pragma unroll
      for (int m = 1; m <= 8; m <<= 1) {
        dacc += __shfl_xor(dacc, m);
        nacc += __shfl_xor(nacc, m);
      }
      if (l15 == 0) {
        atomicAdd(&row_den[ig], dacc);
        atomicAdd(&row_num[ig], nacc);
      }
    }
  }
  if (COL) {
    #pragma unroll
    for (int cb = 0; cb < 4; ++cb) {
      cd[cb] += __shfl_xor(cd[cb], 16);
      cd[cb] += __shfl_xor(cd[cb], 32);
      cn[cb] += __shfl_xor(cn[cb], 16);
      cn[cb] += __shfl_xor(cn[cb], 32);
    }
    if (l < 16) {
      #pragma unroll
      for (int cb = 0; cb < 4; ++cb) {
        atomicAdd(&col_den[j0 + cb*16 + l], cd[cb]);
        atomicAdd(&col_num[j0 + cb*16 + l], cn[cb]);
      }
    }
  }
}

// ---- per-row-block worker (R17: LDS-free): row-block `it`, j-tiles
// jt ≡ c (mod 16), jt >= 2it. A fragments in registers; B fragments read
// DIRECTLY from the fragment-native xh (coalesced dwordx4, L1/L2-resident:
// whole matrix = 4 MB = one XCD's L2). No __syncthreads anywhere.
__device__ __forceinline__ void process_row(
    int it, int c, const char* __restrict__ xb,
    const float* __restrict__ sq, const int* __restrict__ y,
    float nscale2, int l, int wid, int quad, int l15,
    float* __restrict__ row_den, float* __restrict__ row_num,
    float* __restrict__ col_den, float* __restrict__ col_num)
{
  int i0 = it * 128;

  // A fragments: chunk C = it*8 + wid*2 + rb, slice kk, byte l*16
  f16x8 areg[2][8];
  #pragma unroll
  for (int rb = 0; rb < 2; ++rb)
    #pragma unroll
    for (int kk = 0; kk < 8; ++kk)
      areg[rb][kk] = *(const f16x8*)(xb +
          ((size_t)(it*8 + wid*2 + rb) * 8 + kk) * 1024 + l*16);

  int rbase = i0 + wid*32 + quad*4;
  const f32x4 zero4 = {0.f, 0.f, 0.f, 0.f};

  // first j-tile: smallest jt >= 2it with jt ≡ c (mod 16)
  int f = 2*it + ((c - 2*it) & (NCCH-1));

  for (int jt = f; jt < NJTILE; jt += NCCH) {
    int j0 = jt * 64;
    const char* tb = xb + (size_t)jt * 32768;   // 4 chunks-groups of 8 KB

    f32x4 acc[2][4];
    #pragma unroll
    for (int rb = 0; rb < 2; ++rb)
      #pragma unroll
      for (int cb = 0; cb < 4; ++cb)
        acc[rb][cb] = zero4;

    #pragma unroll
    for (int kk = 0; kk < 8; ++kk) {
      f16x8 bv[4];
      #pragma unroll
      for (int cb = 0; cb < 4; ++cb)
        bv[cb] = *(const f16x8*)(tb + cb*8192 + kk*1024 + l*16);
      #pragma unroll
      for (int rb = 0; rb < 2; ++rb)
        #pragma unroll
        for (int cb = 0; cb < 4; ++cb)
          acc[rb][cb] = __builtin_amdgcn_mfma_f32_16x16x32_f16(areg[rb][kk], bv[cb], acc[rb][cb], 0, 0, 0);
    }

    if ((jt >> 1) == it)
      epilogue<true , false>(acc, sq, y, j0, l15, l, rbase, nscale2,
                             row_den, row_num, col_den, col_num);
    else
      epilogue<false, true >(acc, sq, y, j0, l15, l, rbase, nscale2,
                             row_den, row_num, col_den, col_num);
  }
}

// ---- kernel 2 (R17: LDS-free triangular): grid 16 x 32 = 512 blocks.
// Block (c, p) processes row-blocks p then q=63-p (balanced: 8.125 +/- 1
// tiles/block, R15's proven mapping). The 4 MB fp16 matrix L2-fits (guide
// Common-mistake #7: staging L2-fit data is pure overhead) -> B fragments
// read straight from global in fragment-native layout; removes LDS tile,
// both barriers, vmcnt drain, and ALL bank conflicts. Register budget:
// areg 64 + acc 32 + bv 16 + temps ~40 ~= 170 (single-row at a time; the
// dual-row R16/R6b design at ~280 spilled: VGPR=128 + 73 MB scratch WRITE).
__global__ __launch_bounds__(256, 2) void snn_main(
    const unsigned short* __restrict__ xh, const float* __restrict__ sq,
    const int* __restrict__ y, const float* __restrict__ T,
    const float* __restrict__ part_s, const float* __restrict__ part_q,
    float* __restrict__ row_den, float* __restrict__ row_num,
    float* __restrict__ col_den, float* __restrict__ col_num)
{
  int tid = threadIdx.x;
  int l = tid & 63, wid = tid >> 6;     // wid = wave row strip (0..3)
  int quad = l >> 4, l15 = l & 15;
  int c = blockIdx.x, p = blockIdx.y;   // p in [0,32)
  const char* xb = (const char*)xh;

  // scale from prep's 2048 partials (per-wave redundant; no barrier)
  float s_acc = 0.f, q_acc = 0.f;
  #pragma unroll
  for (int t = 0; t < 32; ++t) {
    s_acc += part_s[l + 64*t];
    q_acc += part_q[l + 64*t];
  }
  #pragma unroll
  for (int m = 1; m <= 32; m <<= 1) {
    s_acc += __shfl_xor(s_acc, m);
    q_acc += __shfl_xor(q_acc, m);
  }
  const double n = (double)B_ROWS * FEAT;
  double var = ((double)q_acc - (double)s_acc*(double)s_acc/n) / (n - 1.0);
  float stdv = (float)sqrt(var);
  float p10  = __builtin_amdgcn_exp2f(T[0] * 3.3219280948873623f);
  float nscale2 = -(p10 * 1.4426950408889634f / stdv);

  process_row(p,      c, xb, sq, y, nscale2, l, wid, quad, l15,
              row_den, row_num, col_den, col_num);
  process_row(63 - p, c, xb, sq, y, nscale2, l, wid, quad, l15,
              row_den, row_num, col_den, col_num);
}

// ---- kernel 3: single 1024-thread block; reads only 4 x 32 KB.
// __builtin_amdgcn_logf is LOG2 -> scale by ln(2)  (R4/5/7/9 bug).
__global__ __launch_bounds__(1024) void final_kernel(
    const float* __restrict__ row_den, const float* __restrict__ row_num,
    const float* __restrict__ col_den, const float* __restrict__ col_num,
    float* __restrict__ out)
{
  int tid = threadIdx.x;
  float tot = 0.f;
  #pragma unroll
  for (int rr = 0; rr < 8; ++rr) {
    int row = tid + 1024*rr;
    float den = row_den[row] + col_den[row];
    float num = row_num[row] + col_num[row];
    if (num > 0.f)
      tot += 0.6931471805599453f *
             (__builtin_amdgcn_logf(num) - __builtin_amdgcn_logf(den));
  }
  #pragma unroll
  for (int m = 32; m; m >>= 1) tot += __shfl_xor(tot, m);
  __shared__ float red[16];
  if ((tid & 63) == 0) red[tid >> 6] = tot;
  __syncthreads();
  if (tid == 0) {
    float s = 0.f;
    #pragma unroll
    for (int w = 0; w < 16; ++w) s += red[w];
    out[0] = -s / 8192.0f;
  }
}

extern "C" void kernel_launch(void* const* d_in, const int* in_sizes, int n_in,
                              void* d_out, int out_size, void* d_ws, size_t ws_size,
                              hipStream_t stream)
{
  (void)in_sizes; (void)n_in; (void)out_size; (void)ws_size;
  const float* x  = (const float*)d_in[0];
  const int* y    = (const int*)d_in[1];   // int64 in reference -> int32 here (jax x64 off)
  const float* T  = (const float*)d_in[2];
  char* ws = (char*)d_ws;
  float* part_s = (float*)(ws + 1024);                   // 8 KB
  float* part_q = (float*)(ws + 1024 + 8192);            // 8 KB
  float* sq     = (float*)(ws + 32768);                  // 32 KB
  unsigned short* xh = (unsigned short*)(ws + 65536);    // 4 MB fp16 (fragment layout)
  float* col_den = (float*)(ws + 65536 + 4194304);       // 32 KB
  float* col_num = col_den + B_ROWS;                     // 32 KB
  float* row_den = col_num + B_ROWS;                     // 32 KB
  float* row_num = row_den + B_ROWS;                     // 32 KB

  hipLaunchKernelGGL(prep_kernel, dim3(B_ROWS/4), dim3(256), 0, stream,
                     x, xh, sq, part_s, part_q, col_den, col_num,
                     row_den, row_num);
  hipLaunchKernelGGL(snn_main, dim3(NCCH, 32), dim3(256), 0, stream,
                     xh, sq, y, T, part_s, part_q, row_den, row_num,
                     col_den, col_num);
  hipLaunchKernelGGL(final_kernel, dim3(1), dim3(1024), 0, stream,
                     row_den, row_num, col_den, col_num, (float*)d_out);
}

// Round 9
// 119.051 us; speedup vs baseline: 1.5458x; 1.2193x over previous
//
#include <hip/hip_runtime.h>

#define B_ROWS 8192
#define FEAT   256
#define NBLK   512         // snn blocks; 2080 rounds split into 512 segments
#define NROUND 2080        // 64*65/2 triangular (it<=jr) 128x128 round pairs

typedef float f32x4 __attribute__((ext_vector_type(4)));
typedef _Float16 f16x8 __attribute__((ext_vector_type(8)));

typedef const __attribute__((address_space(1))) unsigned int* gas_ptr;
typedef __attribute__((address_space(3))) unsigned int* las_ptr;

__device__ __forceinline__ void gload_lds16(const void* g, void* l) {
  // HW semantics: LDS dest = wave-uniform base + lane*16 (global src per-lane)
  __builtin_amdgcn_global_load_lds((gas_ptr)g, (las_ptr)l, 16, 0, 0);
}

// ---- kernel 1: fp16 convert -> FRAGMENT-NATIVE layout (R17, proven), row
// ssq, per-block partials; zeroes the atomic accumulators.
// xh chunk(C,kk) [1024 B]: byte l*16 = lane l's MFMA fragment for 16-row
// group C, k-slice kk  (C = row>>4; within: quad*256 + r15*16 + half*8).
__global__ __launch_bounds__(256) void prep_kernel(
    const float* __restrict__ x, unsigned short* __restrict__ xh,
    float* __restrict__ sq, float* __restrict__ part_s,
    float* __restrict__ part_q, float* __restrict__ col_den,
    float* __restrict__ col_num, float* __restrict__ row_den,
    float* __restrict__ row_num)
{
  int tid = threadIdx.x;
  int l = tid & 63, wid = tid >> 6;
  int row = blockIdx.x * 4 + wid;
  const float4* xv = (const float4*)(x + (size_t)row * FEAT);
  float4 v = xv[l];            // cols 4l .. 4l+3
  ushort4 u;
  u.x = __builtin_bit_cast(unsigned short, (_Float16)v.x);
  u.y = __builtin_bit_cast(unsigned short, (_Float16)v.y);
  u.z = __builtin_bit_cast(unsigned short, (_Float16)v.z);
  u.w = __builtin_bit_cast(unsigned short, (_Float16)v.w);
  // k0 = 4l: kk = l>>3, quad = (l>>1)&3, half-of-16B = l&1
  size_t off = ((size_t)(row >> 4) * 8 + (l >> 3)) * 1024
             + ((l >> 1) & 3) * 256 + (row & 15) * 16 + (l & 1) * 8;
  *(ushort4*)((char*)xh + off) = u;
  if (tid < 4) {
    int r4 = blockIdx.x * 4 + tid;
    col_den[r4] = 0.f; col_num[r4] = 0.f;
    row_den[r4] = 0.f; row_num[r4] = 0.f;
  }
  float ssq  = v.x*v.x + v.y*v.y + v.z*v.z + v.w*v.w;
  float ssum = v.x + v.y + v.z + v.w;
  #pragma unroll
  for (int m = 32; m; m >>= 1) {
    ssq  += __shfl_xor(ssq, m);
    ssum += __shfl_xor(ssum, m);
  }
  if (l == 0) sq[row] = ssq;
  __shared__ float red[8];
  if (l == 0) { red[wid*2] = ssum; red[wid*2+1] = ssq; }
  __syncthreads();
  if (tid == 0) {
    part_s[blockIdx.x] = red[0]+red[2]+red[4]+red[6];
    part_q[blockIdx.x] = red[1]+red[3]+red[5]+red[7];
  }
}

// ---- epilogue: wave tile 32(i) x 128(j). Self-contained (R6b/R17 proven):
// row stats re-loaded (quad-uniform, L1-hot); row sums via quad shuffle-
// reduce + atomicAdd; col sums (symmetric credit e(i,j)=e(j,i)) for far
// rounds. DIAG: band round (it==jr), mask i==j, row-sums only.
template<bool DIAG, bool COL>
__device__ __forceinline__ void epilogue(
    const f32x4 (&acc)[2][8], const float* __restrict__ sq,
    const int* __restrict__ y, int j0, int l15, int l,
    int rbase, float nscale2,
    float* __restrict__ row_den, float* __restrict__ row_num,
    float* __restrict__ col_den, float* __restrict__ col_num)
{
  int jb = j0 + l15;
  float sqj[8]; int yj[8];
  #pragma unroll
  for (int cb = 0; cb < 8; ++cb) {
    int j = jb + cb*16;
    sqj[cb] = sq[j];
    yj[cb]  = y[j];
  }
  float cd[8], cn[8];
  if (COL) {
    #pragma unroll
    for (int cb = 0; cb < 8; ++cb) { cd[cb] = 0.f; cn[cb] = 0.f; }
  }
  #pragma unroll
  for (int rb = 0; rb < 2; ++rb) {
    #pragma unroll
    for (int r = 0; r < 4; ++r) {
      int   ig = rbase + rb*16 + r;     // same for all 16 lanes of the quad
      float si = sq[ig];
      int   yi = y[ig];
      float dacc = 0.f, nacc = 0.f;
      #pragma unroll
      for (int cb = 0; cb < 8; ++cb) {
        float S  = acc[rb][cb][r];
        float d2 = fmaf(S, -2.0f, si + sqj[cb]);
        d2 = fmaxf(d2, 0.0f);
        float e  = __builtin_amdgcn_exp2f(__builtin_amdgcn_sqrtf(d2) * nscale2);
        bool same = (yi == yj[cb]);
        bool offd = !DIAG || (ig != jb + cb*16);
        dacc += offd ? e : 0.0f;
        nacc += (same && offd) ? e : 0.0f;
        if (COL) {
          cd[cb] += e;
          cn[cb] += same ? e : 0.0f;
        }
      }
      #pragma unroll
      for (int m = 1; m <= 8; m <<= 1) {
        dacc += __shfl_xor(dacc, m);
        nacc += __shfl_xor(nacc, m);
      }
      if (l15 == 0) {
        atomicAdd(&row_den[ig], dacc);
        atomicAdd(&row_num[ig], nacc);
      }
    }
  }
  if (COL) {
    #pragma unroll
    for (int cb = 0; cb < 8; ++cb) {
      cd[cb] += __shfl_xor(cd[cb], 16);
      cd[cb] += __shfl_xor(cd[cb], 32);
      cn[cb] += __shfl_xor(cn[cb], 16);
      cn[cb] += __shfl_xor(cn[cb], 32);
    }
    if (l < 16) {
      #pragma unroll
      for (int cb = 0; cb < 8; ++cb) {
        atomicAdd(&col_den[j0 + cb*16 + l], cd[cb]);
        atomicAdd(&col_num[j0 + cb*16 + l], cn[cb]);
      }
    }
  }
}

// ---- kernel 2 (R18: panel-resident schedule): the 2080 triangular rounds
// (it<=jr; 128x128 blocks) are flattened sorted-by-jr; block b owns the
// contiguous segment [b*65/16, (b+1)*65/16) -- exactly 4 or 5 rounds
// (perfect balance; fixes R14/R15 makespan). Consecutive rounds share jr,
// so the 64 KB fragment-native B panel is staged ONCE per jr-group
// (~1-2 stagings/block vs ~8 in R15) and rounds within a group run with
// NO barriers: per round = 16 A-fragment loads (L2-hot, overlaps previous
// epilogue) + 128 MFMA + epilogue. ds_reads are base + l*16 + compile-time
// immediate: conflict-free (2-way = free) and ~zero address VALU.
// R17 lesson folded in: LDS-free B was L2-latency-bound (82us, MfmaUtil 8%)
// -- LDS stays, but its barrier cost is amortized ~4-8x.
// Registers: areg 64 + acc 64 + bv 32 + temps ~= 200 < 256 (2 blocks/CU).
__global__ __launch_bounds__(256, 2) void snn_main(
    const unsigned short* __restrict__ xh, const float* __restrict__ sq,
    const int* __restrict__ y, const float* __restrict__ T,
    const float* __restrict__ part_s, const float* __restrict__ part_q,
    float* __restrict__ row_den, float* __restrict__ row_num,
    float* __restrict__ col_den, float* __restrict__ col_num)
{
  __shared__ __align__(16) char lB[65536];
  int tid = threadIdx.x;
  int l = tid & 63, wid = tid >> 6;     // wid = wave row strip (0..3)
  int quad = l >> 4, l15 = l & 15;
  int b = blockIdx.x;
  const char* xb = (const char*)xh;

  // scale from prep's 2048 partials (per-wave redundant; no barrier)
  float s_acc = 0.f, q_acc = 0.f;
  #pragma unroll
  for (int t = 0; t < 32; ++t) {
    s_acc += part_s[l + 64*t];
    q_acc += part_q[l + 64*t];
  }
  #pragma unroll
  for (int m = 1; m <= 32; m <<= 1) {
    s_acc += __shfl_xor(s_acc, m);
    q_acc += __shfl_xor(q_acc, m);
  }
  const double n = (double)B_ROWS * FEAT;
  double var = ((double)q_acc - (double)s_acc*(double)s_acc/n) / (n - 1.0);
  float stdv = (float)sqrt(var);
  float p10  = __builtin_amdgcn_exp2f(T[0] * 3.3219280948873623f);
  float nscale2 = -(p10 * 1.4426950408889634f / stdv);

  // segment [k0, kend) of the flat round list; decode k0 -> (jr, it)
  int k0   = (b * 65) >> 4;
  int kend = ((b + 1) * 65) >> 4;
  int jr = (int)((__builtin_amdgcn_sqrtf(8.f*(float)k0 + 1.f) - 1.f) * 0.5f);
  while ((jr+1)*(jr+2)/2 <= k0) ++jr;
  while (jr*(jr+1)/2 > k0) --jr;
  int it = k0 - jr*(jr+1)/2;

  // stage B panel jr: 64 KB linear (fragment-native src == LDS layout)
  {
    const char* gB = xb + (size_t)jr * 65536;
    #pragma unroll
    for (int s = 0; s < 16; ++s) {
      int cc = wid*16 + s;
      gload_lds16(gB + cc*1024 + l*16, lB + cc*1024);
    }
  }
  __syncthreads();   // drains vmcnt: panel visible

  for (int k = k0; k < kend; ++k) {
    // A fragments for row-block it: chunk C = it*8 + wid*2 + rb, slice kk
    f16x8 areg[2][8];
    #pragma unroll
    for (int rb = 0; rb < 2; ++rb)
      #pragma unroll
      for (int kk = 0; kk < 8; ++kk)
        areg[rb][kk] = *(const f16x8*)(xb +
            ((size_t)(it*8 + wid*2 + rb) * 8 + kk) * 1024 + l*16);

    f32x4 acc[2][8];
    const f32x4 zero4 = {0.f, 0.f, 0.f, 0.f};
    #pragma unroll
    for (int rb = 0; rb < 2; ++rb)
      #pragma unroll
      for (int cb = 0; cb < 8; ++cb)
        acc[rb][cb] = zero4;

    #pragma unroll
    for (int kk = 0; kk < 8; ++kk) {
      f16x8 bv[8];
      #pragma unroll
      for (int cb = 0; cb < 8; ++cb)
        bv[cb] = *(const f16x8*)(lB + (cb*8 + kk)*1024 + l*16);
      #pragma unroll
      for (int rb = 0; rb < 2; ++rb)
        #pragma unroll
        for (int cb = 0; cb < 8; ++cb)
          acc[rb][cb] = __builtin_amdgcn_mfma_f32_16x16x32_f16(areg[rb][kk], bv[cb], acc[rb][cb], 0, 0, 0);
    }

    int j0 = jr * 128;
    int rbase = it*128 + wid*32 + quad*4;
    if (it == jr)
      epilogue<true , false>(acc, sq, y, j0, l15, l, rbase, nscale2,
                             row_den, row_num, col_den, col_num);
    else
      epilogue<false, true >(acc, sq, y, j0, l15, l, rbase, nscale2,
                             row_den, row_num, col_den, col_num);

    ++it;
    if (it > jr && k + 1 < kend) {
      ++jr; it = 0;
      __syncthreads();   // all waves done reading the old panel
      const char* gB = xb + (size_t)jr * 65536;
      #pragma unroll
      for (int s = 0; s < 16; ++s) {
        int cc = wid*16 + s;
        gload_lds16(gB + cc*1024 + l*16, lB + cc*1024);
      }
      __syncthreads();   // drains vmcnt: new panel visible
    }
  }
}

// ---- kernel 3: single 1024-thread block; reads only 4 x 32 KB.
// __builtin_amdgcn_logf is LOG2 -> scale by ln(2)  (R4/5/7/9 bug).
__global__ __launch_bounds__(1024) void final_kernel(
    const float* __restrict__ row_den, const float* __restrict__ row_num,
    const float* __restrict__ col_den, const float* __restrict__ col_num,
    float* __restrict__ out)
{
  int tid = threadIdx.x;
  float tot = 0.f;
  #pragma unroll
  for (int rr = 0; rr < 8; ++rr) {
    int row = tid + 1024*rr;
    float den = row_den[row] + col_den[row];
    float num = row_num[row] + col_num[row];
    if (num > 0.f)
      tot += 0.6931471805599453f *
             (__builtin_amdgcn_logf(num) - __builtin_amdgcn_logf(den));
  }
  #pragma unroll
  for (int m = 32; m; m >>= 1) tot += __shfl_xor(tot, m);
  __shared__ float red[16];
  if ((tid & 63) == 0) red[tid >> 6] = tot;
  __syncthreads();
  if (tid == 0) {
    float s = 0.f;
    #pragma unroll
    for (int w = 0; w < 16; ++w) s += red[w];
    out[0] = -s / 8192.0f;
  }
}

extern "C" void kernel_launch(void* const* d_in, const int* in_sizes, int n_in,
                              void* d_out, int out_size, void* d_ws, size_t ws_size,
                              hipStream_t stream)
{
  (void)in_sizes; (void)n_in; (void)out_size; (void)ws_size;
  const float* x  = (const float*)d_in[0];
  const int* y    = (const int*)d_in[1];   // int64 in reference -> int32 here (jax x64 off)
  const float* T  = (const float*)d_in[2];
  char* ws = (char*)d_ws;
  float* part_s = (float*)(ws + 1024);                   // 8 KB
  float* part_q = (float*)(ws + 1024 + 8192);            // 8 KB
  float* sq     = (float*)(ws + 32768);                  // 32 KB
  unsigned short* xh = (unsigned short*)(ws + 65536);    // 4 MB fp16 (fragment layout)
  float* col_den = (float*)(ws + 65536 + 4194304);       // 32 KB
  float* col_num = col_den + B_ROWS;                     // 32 KB
  float* row_den = col_num + B_ROWS;                     // 32 KB
  float* row_num = row_den + B_ROWS;                     // 32 KB

  hipLaunchKernelGGL(prep_kernel, dim3(B_ROWS/4), dim3(256), 0, stream,
                     x, xh, sq, part_s, part_q, col_den, col_num,
                     row_den, row_num);
  hipLaunchKernelGGL(snn_main, dim3(NBLK), dim3(256), 0, stream,
                     xh, sq, y, T, part_s, part_q, row_den, row_num,
                     col_den, col_num);
  hipLaunchKernelGGL(final_kernel, dim3(1), dim3(1024), 0, stream,
                     row_den, row_num, col_den, col_num, (float*)d_out);
}